// Round 7
// baseline (195.230 us; speedup 1.0000x reference)
//
#include <hip/hip_runtime.h>
#include <hip/hip_bf16.h>

// GCN 2-layer forward for MI355X (gfx950).
// Dtype detected on-device (f32 vs bf16 harness conversion) in kprep b0.
// LESSONS: (R5,R9) LDS-atomic scatter aggregation is ~10x slower than register
// accumulation. (R11) staging must be wave-local. (R12) uint4 gathers with
// oct-per-node halve VMEM instrs at identical line traffic. (R13) barrier-
// coupled multi-phase blocks are straggler-bound. (R14) per-edge global
// atomics in a small-grid kernel are latency-bound. (R15) direct random
// scatter is WRITE-amplified 15x — scatters must stay inside an L2-hot bucket
// window. (R16) decoupled homogeneous dispatches. (R17) pad-to-8 sentinel
// edge lists: tails were not the bottleneck; padding ~free (L1-hot row N).
// (R18) coarse 512-node buckets: neutral (+3us) — reverted to fine 128-node.
// (R19, this round) the stream serializes everything; the only overlap tool
// is role-merging. h1s made UNSCALED (dinv applied at gather via fma with a
// shfl-broadcast dinv[src], f32 — more precise) which breaks kgemm1's dep on
// ksort -> partition and GEMM merge into ONE dispatch (kpg) and overlap.
// Pipeline (5 dispatches):
//   kprep  : b0 = weight canonicalization (W1t frag-packed) + dtype detect;
//            b1 = zero cursor + sentinel rows h1s[N],h2sb[N] + dinv[N]=0
//   kpg    : bid<PB: partition 4096 edges -> etmp[bk*CAP+slot] packed
//            (src<<7)|dstlow (R5-proven); bid>=PB: pure GEMM h1s=x@W1
//            (UNSCALED), 8 waves x 16 rows, B-frags from L2-hot W1t
//   ksort  : block per fine bucket (256 thr): hist -> dinv/rowse(pad-8) ->
//            sentinel fill -> scatter -> esort (L2-hot 8KB window)
//   kagg1f : gather+GEMM2: oct/node, uint4 16B/lane, 8 edges in flight,
//            shfl idx+dinv broadcast, fma accumulate; relu1 rows staged to
//            wave-private LDS; 2 MFMA -> h2sb (pre-scaled)
//   kagg2  : oct per node, uint2 slice, edge-pairs, no tail; width-4 softmax

typedef unsigned short u16;
typedef __attribute__((ext_vector_type(8))) short short8;   // 8 bf16
typedef __attribute__((ext_vector_type(4))) float f32x4;

#define CAP 4096    // fine bucket: ~2046 edges + <=128*7 pad slots < 4096

__device__ __forceinline__ float bf2f(u16 u) {
  return __uint_as_float(((unsigned int)u) << 16);
}
__device__ __forceinline__ u16 f2bf(float f) {
  unsigned int u = __float_as_uint(f);
  u += 0x7fffu + ((u >> 16) & 1u);
  return (u16)(u >> 16);
}
__device__ __forceinline__ float blo(unsigned int u) {
  return __uint_as_float(u << 16);
}
__device__ __forceinline__ float bhi(unsigned int u) {
  return __uint_as_float(u & 0xffff0000u);
}

// ---- kprep: b0 = weights + mode; b1 = cursor zero + sentinels ----
__global__ __launch_bounds__(512) void kprep(
    const void* __restrict__ W1r, const void* __restrict__ b1r,
    const void* __restrict__ W2r, const void* __restrict__ b2r,
    u16* __restrict__ W1t, float* __restrict__ b1f, u16* __restrict__ W2b,
    float* __restrict__ b2f, int* __restrict__ mode, int* __restrict__ cursor,
    int NB, u16* __restrict__ h1s, u16* __restrict__ h2sb,
    float* __restrict__ dinv, int N) {
  int tid = threadIdx.x;
  if (blockIdx.x == 1) {
    for (int i = tid; i < NB; i += 512) cursor[i] = 0;
    if (tid < 8) ((uint4*)h1s)[(size_t)N * 8 + tid] = make_uint4(0, 0, 0, 0);
    if (tid < 2) ((uint4*)h2sb)[(size_t)N * 2 + tid] = make_uint4(0, 0, 0, 0);
    if (tid == 0) dinv[N] = 0.f;          // sentinel scale (fma guard)
    return;
  }
  __shared__ float red[8];
  __shared__ int smode;
  const u16* w = (const u16*)W1r;
  float mx = 0.f;
  for (int i = tid; i < 8192; i += 512) {
    float av = fabsf(bf2f(w[i]));
    if (!(av <= 1e6f)) av = 3e38f;
    mx = fmaxf(mx, av);
  }
  #pragma unroll
  for (int off = 32; off >= 1; off >>= 1) mx = fmaxf(mx, __shfl_xor(mx, off, 64));
  if ((tid & 63) == 0) red[tid >> 6] = mx;
  __syncthreads();
  if (tid == 0) {
    float m2 = 0.f;
    #pragma unroll
    for (int wv = 0; wv < 8; ++wv) m2 = fmaxf(m2, red[wv]);
    smode = (m2 > 1e6f) ? 1 : 0;
    mode[0] = smode;
  }
  __syncthreads();
  int m = smode;
  // W1t: fragment-packed. i = f*512 + l*8 + j; f=(kb*4+jb), l=(q*16+m16).
  // element = W1[k = kb*32+q*8+j][n = jb*16+m16]
  for (int i = tid; i < 8192; i += 512) {
    int f = i >> 9, l = (i >> 3) & 63, j = i & 7;
    int k = (f >> 2) * 32 + (l >> 4) * 8 + j;
    int n = (f & 3) * 16 + (l & 15);
    int s = k * 64 + n;
    W1t[i] = m ? f2bf(((const float*)W1r)[s]) : ((const u16*)W1r)[s];
  }
  for (int i = tid; i < 1024; i += 512)
    W2b[i] = m ? f2bf(((const float*)W2r)[i]) : ((const u16*)W2r)[i];
  if (tid < 64) b1f[tid] = m ? ((const float*)b1r)[tid] : bf2f(((const u16*)b1r)[tid]);
  if (tid < 16) b2f[tid] = m ? ((const float*)b2r)[tid] : bf2f(((const u16*)b2r)[tid]);
}

// ---- kpg: bid<PB = edge partition (R5-proven); bid>=PB = pure GEMM ----
__global__ __launch_bounds__(512) void kpg(
    const int* __restrict__ src, const int* __restrict__ dst,
    int* __restrict__ cursor, int* __restrict__ etmp,
    const void* __restrict__ xraw, const u16* __restrict__ W1t,
    const int* __restrict__ mode, u16* __restrict__ h1s,
    int E, int NB, int PB, int N) {
  __shared__ int hist[1024], basep[1024];
  int tid = threadIdx.x;
  int bid = blockIdx.x;

  if (bid < PB) {
    // ---- partition role: 8 edges/thread, 4096 edges/block ----
    for (int i = tid; i < 1024; i += 512) hist[i] = 0;
    __syncthreads();
    int e0 = bid * 4096 + tid * 8;
    int pk[8], off[8], cb[8];
    if (e0 + 7 < E) {
      int4 s4[2], d4[2];
      #pragma unroll
      for (int u = 0; u < 2; ++u) {
        s4[u] = ((const int4*)(src + e0))[u];
        d4[u] = ((const int4*)(dst + e0))[u];
      }
      const int* sp = (const int*)s4;
      const int* dp = (const int*)d4;
      #pragma unroll
      for (int k = 0; k < 8; ++k) {
        int s = sp[k], d = dp[k];
        cb[k] = d >> 7;
        pk[k] = (s << 7) | (d & 127);
        off[k] = atomicAdd(&hist[cb[k]], 1);
      }
    } else {
      #pragma unroll
      for (int k = 0; k < 8; ++k) {
        int e = e0 + k;
        cb[k] = -1;
        if (e < E) {
          int s = src[e], d = dst[e];
          cb[k] = d >> 7;
          pk[k] = (s << 7) | (d & 127);
          off[k] = atomicAdd(&hist[cb[k]], 1);
        }
      }
    }
    __syncthreads();
    for (int i = tid; i < NB; i += 512)
      if (hist[i]) basep[i] = atomicAdd(&cursor[i], hist[i]);
    __syncthreads();
    if (e0 + 7 < E) {
      #pragma unroll
      for (int k = 0; k < 8; ++k)
        etmp[cb[k] * CAP + basep[cb[k]] + off[k]] = pk[k];
    } else {
      #pragma unroll
      for (int k = 0; k < 8; ++k)
        if (cb[k] >= 0) etmp[cb[k] * CAP + basep[cb[k]] + off[k]] = pk[k];
    }
    return;
  }

  // ---- GEMM role: h1s = x @ W1 (UNSCALED), 8 waves x 16 rows ----
  int g = bid - PB;
  int mflag = mode[0];
  int lane = tid & 63, wv = tid >> 6;
  int m16 = lane & 15, q = lane >> 4;
  int row0 = g * 128 + wv * 16;

  f32x4 acc[4];
  #pragma unroll
  for (int jb = 0; jb < 4; ++jb) acc[jb] = (f32x4){0.f, 0.f, 0.f, 0.f};

  int rowm = row0 + m16;
  size_t rc = (size_t)((rowm < N) ? rowm : (N - 1));   // clamp loads only
  #pragma unroll
  for (int kb = 0; kb < 4; ++kb) {
    short8 a;
    if (mflag) {
      const float* xf = (const float*)xraw + rc * 128 + kb * 32 + q * 8;
      float4 u0 = ((const float4*)xf)[0];
      float4 u1 = ((const float4*)xf)[1];
      __hip_bfloat162 p0 = __float22bfloat162_rn(make_float2(u0.x, u0.y));
      __hip_bfloat162 p1 = __float22bfloat162_rn(make_float2(u0.z, u0.w));
      __hip_bfloat162 p2 = __float22bfloat162_rn(make_float2(u1.x, u1.y));
      __hip_bfloat162 p3 = __float22bfloat162_rn(make_float2(u1.z, u1.w));
      unsigned int w0 = *(const unsigned int*)&p0;
      unsigned int w1 = *(const unsigned int*)&p1;
      unsigned int w2 = *(const unsigned int*)&p2;
      unsigned int w3 = *(const unsigned int*)&p3;
      a[0] = (short)(w0 & 0xffff); a[1] = (short)(w0 >> 16);
      a[2] = (short)(w1 & 0xffff); a[3] = (short)(w1 >> 16);
      a[4] = (short)(w2 & 0xffff); a[5] = (short)(w2 >> 16);
      a[6] = (short)(w3 & 0xffff); a[7] = (short)(w3 >> 16);
    } else {
      a = *(const short8*)((const u16*)xraw + rc * 128 + kb * 32 + q * 8);
    }
    #pragma unroll
    for (int jb = 0; jb < 4; ++jb) {
      short8 bwf = *(const short8*)(W1t + (size_t)((kb * 4 + jb) * 64 + lane) * 8);
      acc[jb] = __builtin_amdgcn_mfma_f32_16x16x32_bf16(a, bwf, acc[jb], 0, 0, 0);
    }
  }

  #pragma unroll
  for (int r = 0; r < 4; ++r) {
    int rr = row0 + q * 4 + r;
    if (rr < N) {
      #pragma unroll
      for (int jb = 0; jb < 4; ++jb)
        h1s[(size_t)rr * 64 + jb * 16 + m16] = f2bf(acc[jb][r]);
    }
  }
}

// Counting sort per fine bucket with 8-slot padding (1.5KB LDS, 256 thr).
__global__ __launch_bounds__(256) void ksort(
    const int* __restrict__ etmp, const int* __restrict__ cursor,
    float* __restrict__ dinv, int* __restrict__ esort,
    int2* __restrict__ rowse, int N) {
  __shared__ int hist[128], starts[128], curs[128];
  int tid = threadIdx.x;
  int bk = blockIdx.x;
  int base = bk * CAP;
  int cnt = cursor[bk];
  int node0 = bk << 7;

  if (tid < 128) hist[tid] = 0;
  __syncthreads();
  for (int i = tid; i < cnt; i += 256)
    atomicAdd(&hist[etmp[base + i] & 127], 1);
  __syncthreads();
  if (tid < 64) {
    int v0 = hist[tid], v1 = hist[tid + 64];
    int p0 = (v0 + 7) & ~7, p1 = (v1 + 7) & ~7;   // padded counts
    int s0 = p0;
    #pragma unroll
    for (int off = 1; off < 64; off <<= 1) {
      int t = __shfl_up(s0, off, 64);
      if (tid >= off) s0 += t;
    }
    int tot0 = __shfl(s0, 63, 64);
    int s1 = p1;
    #pragma unroll
    for (int off = 1; off < 64; off <<= 1) {
      int t = __shfl_up(s1, off, 64);
      if (tid >= off) s1 += t;
    }
    s1 += tot0;
    int st0 = s0 - p0, st1 = s1 - p1;
    starts[tid] = st0;       starts[tid + 64] = st1;
    curs[tid] = st0;         curs[tid + 64] = st1;
    int n0 = node0 + tid, n1 = n0 + 64;
    if (n0 < N) {
      rowse[n0] = make_int2(base + st0, base + st0 + p0);   // padded range
      dinv[n0] = rsqrtf((float)(v0 + 1));
    }
    if (n1 < N) {
      rowse[n1] = make_int2(base + st1, base + st1 + p1);
      dinv[n1] = rsqrtf((float)(v1 + 1));
    }
  }
  __syncthreads();
  // sentinel-fill pad slots [start+v, start+p) — disjoint from scatter range
  if (tid < 128) {
    int v = hist[tid], st = starts[tid];
    int p = (v + 7) & ~7;
    for (int j = v; j < p; ++j) esort[base + st + j] = N;
  }
  for (int i = tid; i < cnt; i += 256) {
    int pk = etmp[base + i];
    int pos = atomicAdd(&curs[pk & 127], 1);
    esort[base + pos] = pk >> 7;
  }
}

// Layer-1 aggregate (fma with dinv[src]) + relu + MFMA GEMM2. 256 thr = 4
// waves, 64 nodes/block, no __syncthreads. Oct per node; lane fl owns
// features 8fl..8fl+7 (uint4). Pure 8-deep chunk loop, idx+scale via shfl.
__global__ __launch_bounds__(256) void kagg1f(
    const u16* __restrict__ h1s, const int* __restrict__ esort,
    const int2* __restrict__ rowse, const float* __restrict__ dinv,
    const float* __restrict__ b1f, const u16* __restrict__ W2b,
    u16* __restrict__ h2sb, int N) {
  __shared__ __align__(16) u16 sA[4][16 * 72];  // wave-private bf16 tiles (9.2 KB)
  __shared__ float sdv[4][16];
  int tid = threadIdx.x;
  int lane = tid & 63, wv = tid >> 6;
  int o = lane >> 3, fl = lane & 7;             // oct index, feature-slice lane
  int wbase = blockIdx.x * 64 + wv * 16;        // this wave's 16 nodes

  const uint4* __restrict__ h1v4 = (const uint4*)h1s;

  #pragma unroll
  for (int sub = 0; sub < 2; ++sub) {
    int nloc = sub * 8 + o;
    int node = wbase + nloc;
    int cn = (node < N) ? node : (N - 1);       // clamp loads only
    int2 se = (node < N) ? rowse[node] : make_int2(0, 0);
    int beg = se.x, end = se.y;                 // padded range, multiple of 8
    float a0 = 0.f, a1 = 0.f, a2 = 0.f, a3 = 0.f;
    float a4 = 0.f, a5 = 0.f, a6 = 0.f, a7 = 0.f;

    int k = beg;
    int myi = (k < end) ? esort[k + fl] : 0;    // coalesced: 8 lanes, 8 ints
    float myd = (k < end) ? dinv[myi] : 0.f;    // per-edge scale (dinv[N]=0)
    while (k < end) {
      int cur = myi;
      float curd = myd;
      int kn = k + 8;
      if (kn < end) {                            // prefetch next chunk
        myi = esort[kn + fl];
        myd = dinv[myi];
      }
      uint4 g[8];
      float dvp[8];
      #pragma unroll
      for (int p = 0; p < 8; ++p) {
        int s = __shfl(cur, (o << 3) + p, 64);   // broadcast within oct
        dvp[p] = __shfl(curd, (o << 3) + p, 64);
        g[p] = h1v4[s * 8 + fl];                 // s==N -> zero sentinel row
      }
      #pragma unroll
      for (int p = 0; p < 8; ++p) {
        a0 = fmaf(dvp[p], blo(g[p].x), a0); a1 = fmaf(dvp[p], bhi(g[p].x), a1);
        a2 = fmaf(dvp[p], blo(g[p].y), a2); a3 = fmaf(dvp[p], bhi(g[p].y), a3);
        a4 = fmaf(dvp[p], blo(g[p].z), a4); a5 = fmaf(dvp[p], bhi(g[p].z), a5);
        a6 = fmaf(dvp[p], blo(g[p].w), a6); a7 = fmaf(dvp[p], bhi(g[p].w), a7);
      }
      k = kn;
    }

    uint4 sg = h1v4[cn * 8 + fl];                // self row (UNSCALED)
    float dv = dinv[cn];
    float dv2 = dv * dv;
    float4 bva = ((const float4*)b1f)[fl * 2];
    float4 bvb = ((const float4*)b1f)[fl * 2 + 1];
    float v0 = fmaxf(dv * a0 + dv2 * blo(sg.x) + bva.x, 0.f);
    float v1 = fmaxf(dv * a1 + dv2 * bhi(sg.x) + bva.y, 0.f);
    float v2 = fmaxf(dv * a2 + dv2 * blo(sg.y) + bva.z, 0.f);
    float v3 = fmaxf(dv * a3 + dv2 * bhi(sg.y) + bva.w, 0.f);
    float v4 = fmaxf(dv * a4 + dv2 * blo(sg.z) + bvb.x, 0.f);
    float v5 = fmaxf(dv * a5 + dv2 * bhi(sg.z) + bvb.y, 0.f);
    float v6 = fmaxf(dv * a6 + dv2 * blo(sg.w) + bvb.z, 0.f);
    float v7 = fmaxf(dv * a7 + dv2 * bhi(sg.w) + bvb.w, 0.f);
    uint4 st;
    st.x = (unsigned int)f2bf(v0) | ((unsigned int)f2bf(v1) << 16);
    st.y = (unsigned int)f2bf(v2) | ((unsigned int)f2bf(v3) << 16);
    st.z = (unsigned int)f2bf(v4) | ((unsigned int)f2bf(v5) << 16);
    st.w = (unsigned int)f2bf(v6) | ((unsigned int)f2bf(v7) << 16);
    *(uint4*)&sA[wv][nloc * 72 + fl * 8] = st;   // 144B row stride, 16B aligned
    if (fl == 0) sdv[wv][nloc] = dv;
  }

  // GEMM2 B-frags built late to shrink live range (W2b is L2-hot).
  int m16 = lane & 15, q = lane >> 4;
  short8 bw0, bw1;
  #pragma unroll
  for (int j = 0; j < 8; ++j) {
    bw0[j] = (short)W2b[(q * 8 + j) * 16 + m16];
    bw1[j] = (short)W2b[(32 + q * 8 + j) * 16 + m16];
  }
  __builtin_amdgcn_wave_barrier();               // order LDS write->read in-wave

  // MFMA: A[m=node 0..15][k=feature], one 16-node tile per wave.
  const u16* ar = &sA[wv][m16 * 72];
  short8 af0 = *(const short8*)(ar + q * 8);     // k = q*8+j
  short8 af1 = *(const short8*)(ar + 32 + q * 8);
  f32x4 c = (f32x4){0.f, 0.f, 0.f, 0.f};
  c = __builtin_amdgcn_mfma_f32_16x16x32_bf16(af0, bw0, c, 0, 0, 0);
  c = __builtin_amdgcn_mfma_f32_16x16x32_bf16(af1, bw1, c, 0, 0, 0);
  #pragma unroll
  for (int r = 0; r < 4; ++r) {
    int nloc2 = q * 4 + r;                       // D row = q*4+r, col = m16
    int nd2 = wbase + nloc2;
    if (nd2 < N) h2sb[(size_t)nd2 * 16 + m16] = f2bf(c[r] * sdv[wv][nloc2]);
  }
}

// Layer-2 aggregate + bias + relu + log_softmax (h2sb pre-scaled).
__global__ __launch_bounds__(256) void kagg2(
    const u16* __restrict__ h2sb, const int* __restrict__ esort,
    const int2* __restrict__ rowse, const float* __restrict__ dinv,
    const float* __restrict__ b2f, const int* __restrict__ mode,
    void* __restrict__ out, int n) {
  int mflag = mode[0];
  int tid = threadIdx.x;
  int lane = tid & 63, wv = tid >> 6;
  int oc = lane >> 3, ol = lane & 7;
  int hl = ol >> 2, fl = ol & 3;
  int node = blockIdx.x * 32 + wv * 8 + oc;
  if (node >= n) node = n - 1;
  int2 se = rowse[node];
  int beg = se.x, end = se.y;              // padded range, multiple of 8
  const uint2* h2v = (const uint2*)h2sb;   // 4 uint2 per 16-class row
  uint2 sg = h2v[node * 4 + fl];
  float a0 = 0.f, a1 = 0.f, a2 = 0.f, a3 = 0.f;

  for (int k = beg; k < end; k += 8) {     // 4 loads (8 edges) in flight
    int i0 = esort[k + hl], i1 = esort[k + 2 + hl];
    int i2 = esort[k + 4 + hl], i3 = esort[k + 6 + hl];
    uint2 g0 = h2v[i0 * 4 + fl];
    uint2 g1 = h2v[i1 * 4 + fl];
    uint2 g2 = h2v[i2 * 4 + fl];
    uint2 g3 = h2v[i3 * 4 + fl];
    a0 += bf2f((u16)(g0.x & 0xffff)) + bf2f((u16)(g1.x & 0xffff))
        + bf2f((u16)(g2.x & 0xffff)) + bf2f((u16)(g3.x & 0xffff));
    a1 += bf2f((u16)(g0.x >> 16)) + bf2f((u16)(g1.x >> 16))
        + bf2f((u16)(g2.x >> 16)) + bf2f((u16)(g3.x >> 16));
    a2 += bf2f((u16)(g0.y & 0xffff)) + bf2f((u16)(g1.y & 0xffff))
        + bf2f((u16)(g2.y & 0xffff)) + bf2f((u16)(g3.y & 0xffff));
    a3 += bf2f((u16)(g0.y >> 16)) + bf2f((u16)(g1.y >> 16))
        + bf2f((u16)(g2.y >> 16)) + bf2f((u16)(g3.y >> 16));
  }
  // combine edge-parity halves (lanes +-4 within the oct)
  a0 += __shfl_xor(a0, 4, 8);  a1 += __shfl_xor(a1, 4, 8);
  a2 += __shfl_xor(a2, 4, 8);  a3 += __shfl_xor(a3, 4, 8);

  float dv = dinv[node];
  float4 bv = ((const float4*)b2f)[fl];
  float v0 = fmaxf(dv * (a0 + bf2f((u16)(sg.x & 0xffff))) + bv.x, 0.f);
  float v1 = fmaxf(dv * (a1 + bf2f((u16)(sg.x >> 16))) + bv.y, 0.f);
  float v2 = fmaxf(dv * (a2 + bf2f((u16)(sg.y & 0xffff))) + bv.z, 0.f);
  float v3 = fmaxf(dv * (a3 + bf2f((u16)(sg.y >> 16))) + bv.w, 0.f);

  float m = fmaxf(fmaxf(v0, v1), fmaxf(v2, v3));
  m = fmaxf(m, __shfl_xor(m, 1, 4));
  m = fmaxf(m, __shfl_xor(m, 2, 4));
  float ex = __expf(v0 - m) + __expf(v1 - m) + __expf(v2 - m) + __expf(v3 - m);
  ex += __shfl_xor(ex, 1, 4);
  ex += __shfl_xor(ex, 2, 4);
  float lg = __logf(ex);
  float r0 = v0 - m - lg, r1 = v1 - m - lg;
  float r2 = v2 - m - lg, r3 = v3 - m - lg;
  if (hl == 0) {
    if (mflag) {
      ((float4*)out)[(size_t)node * 4 + fl] = make_float4(r0, r1, r2, r3);
    } else {
      uint2 o;
      o.x = (unsigned int)f2bf(r0) | ((unsigned int)f2bf(r1) << 16);
      o.y = (unsigned int)f2bf(r2) | ((unsigned int)f2bf(r3) << 16);
      ((uint2*)out)[(size_t)node * 4 + fl] = o;
    }
  }
}

extern "C" void kernel_launch(void* const* d_in, const int* in_sizes, int n_in,
                              void* d_out, int out_size, void* d_ws, size_t ws_size,
                              hipStream_t stream) {
  const void* x  = d_in[0];
  const int* ei  = (const int*)d_in[1];
  const void* W1 = d_in[2];
  const void* b1 = d_in[3];
  const void* W2 = d_in[4];
  const void* b2 = d_in[5];

  const int N = in_sizes[0] / 128;
  const int E = in_sizes[1] / 2;
  const int* src = ei;
  const int* dst = ei + E;
  const int NB = (N + 127) >> 7;          // 128-node fine buckets
  const int PB = (E + 4095) / 4096;       // partition blocks
  const int GB = (N + 127) / 128;         // GEMM blocks (128 rows each)

  char* ws = (char*)d_ws;
  size_t off = 0;
  auto alloc = [&](size_t bytes) -> char* {
    char* p = ws + off;
    off = (off + bytes + 255) & ~(size_t)255;
    return p;
  };
  u16*   h1s    = (u16*)  alloc((size_t)(N + 1) * 64 * 2);  // +1 sentinel row
  u16*   h2sb   = (u16*)  alloc((size_t)(N + 1) * 16 * 2);  // +1 sentinel row
  int*   etmp   = (int*)  alloc((size_t)NB * CAP * 4);
  int*   esort  = (int*)  alloc((size_t)NB * CAP * 4);
  int2*  rowse  = (int2*) alloc((size_t)N * 8);
  float* dinv   = (float*)alloc((size_t)(N + 8) * 4);       // +sentinel slot
  int*   cursor = (int*)  alloc((size_t)NB * 4);
  u16*   W1t    = (u16*)  alloc(8192 * 2);
  u16*   W2b    = (u16*)  alloc(1024 * 2);
  float* b1f    = (float*)alloc(64 * 4);
  float* b2f    = (float*)alloc(16 * 4);
  int*   mode   = (int*)  alloc(4);

  kprep<<<2, 512, 0, stream>>>(W1, b1, W2, b2, W1t, b1f, W2b, b2f, mode,
                               cursor, NB, h1s, h2sb, dinv, N);
  kpg<<<PB + GB, 512, 0, stream>>>(src, dst, cursor, etmp, x, W1t, mode,
                                   h1s, E, NB, PB, N);
  ksort<<<NB, 256, 0, stream>>>(etmp, cursor, dinv, esort, rowse, N);
  kagg1f<<<(N + 63) / 64, 256, 0, stream>>>(h1s, esort, rowse, dinv, b1f, W2b,
                                            h2sb, N);
  kagg2<<<(N + 31) / 32, 256, 0, stream>>>(h2sb, esort, rowse, dinv, b2f, mode,
                                           d_out, N);
}

// Round 8
// 187.916 us; speedup vs baseline: 1.0389x; 1.0389x over previous
//
#include <hip/hip_runtime.h>
#include <hip/hip_bf16.h>

// GCN 2-layer forward for MI355X (gfx950).
// Dtype detected on-device (f32 vs bf16 harness conversion), inside kpartc b0.
// Rows pre-scaled by dinv so aggregation is a plain sum.
// LESSONS: (R5,R9) LDS-atomic scatter aggregation is ~10x slower than register
// accumulation. (R11) staging must be wave-local. (R12) uint4 gathers with
// oct-per-node halve VMEM instrs at identical line traffic. (R13) barrier-
// coupled multi-phase blocks are straggler-bound. (R14) per-edge global
// atomics in a small-grid kernel are latency-bound. (R15) direct random
// scatter is WRITE-amplified 15x — scatters must stay inside an L2-hot bucket
// window. (R16) decoupled homogeneous dispatches. (R17) pad-to-8 sentinel
// edge lists: tails were NOT the bottleneck (-1.7us) => gathers are
// THROUGHPUT-bound at the L3 floor; gather kernels frozen. (R18) coarse
// 512-node buckets: neutral. (R19) kpg role-merge + unscaled h1s: +6.6us
// (extra dinv load/shfl/fma in the hot gather loop) — reverted to R5.
// (R20, this round) R5 base; ksort reads the bucket ONCE: stage packed edges
// in LDS during the histogram pass (R0/R1-proven eL), scatter from LDS.
// Pipeline (6 dispatches incl. memset):
//   kpartc : block0 = weight canonicalization (W1t frag-packed) + dtype
//            detect; other blocks partition edges -> etmp[bk*CAP+slot]
//            packed (src<<7)|dstlow, bucket-local coalesced writes
//   ksort  : block per bucket, 17.5KB LDS: stage+hist -> dinv/rowse(pad-8) ->
//            sentinel fill -> scatter from LDS -> esort (L2-hot window)
//   kgemm1 : pure GEMM h1s = (x@W1)*dinv, 256 thr, 64 rows, no LDS, no
//            barriers; B-frags one dwordx4 each from L2-hot frag-packed W1t
//   kagg1f : pure gather+GEMM2: 256 thr, 64 nodes/block, no __syncthreads.
//            Oct per node, uint4 16B/lane, 8 edges in flight, shfl-broadcast
//            indices, no tail; bf16 row to wave-private LDS; 2 MFMA -> h2sb
//   kagg2  : oct per node, uint2 slice, edge-pairs, no tail; width-4 softmax

typedef unsigned short u16;
typedef __attribute__((ext_vector_type(8))) short short8;   // 8 bf16
typedef __attribute__((ext_vector_type(4))) float f32x4;

#define CAP 4096    // bucket: ~2046 edges + <=128*7 pad slots < 4096

__device__ __forceinline__ float bf2f(u16 u) {
  return __uint_as_float(((unsigned int)u) << 16);
}
__device__ __forceinline__ u16 f2bf(float f) {
  unsigned int u = __float_as_uint(f);
  u += 0x7fffu + ((u >> 16) & 1u);
  return (u16)(u >> 16);
}
__device__ __forceinline__ float blo(unsigned int u) {
  return __uint_as_float(u << 16);
}
__device__ __forceinline__ float bhi(unsigned int u) {
  return __uint_as_float(u & 0xffff0000u);
}

// ---- merged: block 0 = weight canonicalization + dtype detect;
//      blocks 1.. = edge partition into padded buckets (4096 edges/block) ----
__global__ __launch_bounds__(512) void kpartc(
    const int* __restrict__ src, const int* __restrict__ dst,
    int* __restrict__ cursor, int* __restrict__ etmp,
    const void* __restrict__ W1r, const void* __restrict__ b1r,
    const void* __restrict__ W2r, const void* __restrict__ b2r,
    u16* __restrict__ W1t, float* __restrict__ b1f, u16* __restrict__ W2b,
    float* __restrict__ b2f, int* __restrict__ mode, int E, int NB) {
  __shared__ int hist[1024], basep[1024];
  __shared__ float red[8];
  __shared__ int smode;
  int tid = threadIdx.x;

  if (blockIdx.x == 0) {
    // ---- conv role ----
    const u16* w = (const u16*)W1r;
    float mx = 0.f;
    for (int i = tid; i < 8192; i += 512) {
      float av = fabsf(bf2f(w[i]));
      if (!(av <= 1e6f)) av = 3e38f;
      mx = fmaxf(mx, av);
    }
    #pragma unroll
    for (int off = 32; off >= 1; off >>= 1) mx = fmaxf(mx, __shfl_xor(mx, off, 64));
    if ((tid & 63) == 0) red[tid >> 6] = mx;
    __syncthreads();
    if (tid == 0) {
      float m2 = 0.f;
      #pragma unroll
      for (int wv = 0; wv < 8; ++wv) m2 = fmaxf(m2, red[wv]);
      smode = (m2 > 1e6f) ? 1 : 0;
      mode[0] = smode;
    }
    __syncthreads();
    int m = smode;
    // W1t: fragment-packed. i = f*512 + l*8 + j; f=(kb*4+jb), l=(q*16+m16).
    // element = W1[k = kb*32+q*8+j][n = jb*16+m16]
    for (int i = tid; i < 8192; i += 512) {
      int f = i >> 9, l = (i >> 3) & 63, j = i & 7;
      int k = (f >> 2) * 32 + (l >> 4) * 8 + j;
      int n = (f & 3) * 16 + (l & 15);
      int s = k * 64 + n;
      W1t[i] = m ? f2bf(((const float*)W1r)[s]) : ((const u16*)W1r)[s];
    }
    for (int i = tid; i < 1024; i += 512)
      W2b[i] = m ? f2bf(((const float*)W2r)[i]) : ((const u16*)W2r)[i];
    if (tid < 64) b1f[tid] = m ? ((const float*)b1r)[tid] : bf2f(((const u16*)b1r)[tid]);
    if (tid < 16) b2f[tid] = m ? ((const float*)b2r)[tid] : bf2f(((const u16*)b2r)[tid]);
    return;
  }

  // ---- partition role: 8 edges/thread (2x TLP vs 16) ----
  for (int i = tid; i < 1024; i += 512) hist[i] = 0;
  __syncthreads();
  int e0 = (blockIdx.x - 1) * 4096 + tid * 8;
  int pk[8], off[8], cb[8];
  if (e0 + 7 < E) {
    int4 s4[2], d4[2];
    #pragma unroll
    for (int u = 0; u < 2; ++u) {
      s4[u] = ((const int4*)(src + e0))[u];
      d4[u] = ((const int4*)(dst + e0))[u];
    }
    const int* sp = (const int*)s4;
    const int* dp = (const int*)d4;
    #pragma unroll
    for (int k = 0; k < 8; ++k) {
      int s = sp[k], d = dp[k];
      cb[k] = d >> 7;
      pk[k] = (s << 7) | (d & 127);
      off[k] = atomicAdd(&hist[cb[k]], 1);
    }
  } else {
    #pragma unroll
    for (int k = 0; k < 8; ++k) {
      int e = e0 + k;
      cb[k] = -1;
      if (e < E) {
        int s = src[e], d = dst[e];
        cb[k] = d >> 7;
        pk[k] = (s << 7) | (d & 127);
        off[k] = atomicAdd(&hist[cb[k]], 1);
      }
    }
  }
  __syncthreads();
  for (int i = tid; i < NB; i += 512)
    if (hist[i]) basep[i] = atomicAdd(&cursor[i], hist[i]);
  __syncthreads();
  if (e0 + 7 < E) {
    #pragma unroll
    for (int k = 0; k < 8; ++k)
      etmp[cb[k] * CAP + basep[cb[k]] + off[k]] = pk[k];
  } else {
    #pragma unroll
    for (int k = 0; k < 8; ++k)
      if (cb[k] >= 0) etmp[cb[k] * CAP + basep[cb[k]] + off[k]] = pk[k];
  }
}

// Counting sort per bucket with 8-slot padding. ONE global pass (R20): the
// bucket's packed edges are staged into LDS during the histogram pass and the
// scatter runs from LDS. 17.5KB LDS, 256 thr.
// Block 0 additionally zeroes the sentinel rows h1s[N], h2sb[N].
__global__ __launch_bounds__(256) void ksort(
    const int* __restrict__ etmp, const int* __restrict__ cursor,
    float* __restrict__ dinv, int* __restrict__ esort,
    int2* __restrict__ rowse, u16* __restrict__ h1s, u16* __restrict__ h2sb,
    int N) {
  __shared__ int eL[CAP];                 // staged packed edges (16 KB)
  __shared__ int hist[128], starts[128], curs[128];
  int tid = threadIdx.x;
  int bk = blockIdx.x;
  int base = bk * CAP;
  int cnt = cursor[bk];
  int node0 = bk << 7;

  if (bk == 0) {   // zero sentinel rows (gathers of pad slots read these)
    if (tid < 8) ((uint4*)h1s)[(size_t)N * 8 + tid] = make_uint4(0, 0, 0, 0);
    if (tid < 2) ((uint4*)h2sb)[(size_t)N * 2 + tid] = make_uint4(0, 0, 0, 0);
  }

  if (tid < 128) hist[tid] = 0;
  __syncthreads();
  for (int i = tid; i < cnt; i += 256) {
    int pk = etmp[base + i];
    eL[i] = pk;
    atomicAdd(&hist[pk & 127], 1);
  }
  __syncthreads();
  if (tid < 64) {
    int v0 = hist[tid], v1 = hist[tid + 64];
    int p0 = (v0 + 7) & ~7, p1 = (v1 + 7) & ~7;   // padded counts
    int s0 = p0;
    #pragma unroll
    for (int off = 1; off < 64; off <<= 1) {
      int t = __shfl_up(s0, off, 64);
      if (tid >= off) s0 += t;
    }
    int tot0 = __shfl(s0, 63, 64);
    int s1 = p1;
    #pragma unroll
    for (int off = 1; off < 64; off <<= 1) {
      int t = __shfl_up(s1, off, 64);
      if (tid >= off) s1 += t;
    }
    s1 += tot0;
    int st0 = s0 - p0, st1 = s1 - p1;
    starts[tid] = st0;       starts[tid + 64] = st1;
    curs[tid] = st0;         curs[tid + 64] = st1;
    int n0 = node0 + tid, n1 = n0 + 64;
    if (n0 < N) {
      rowse[n0] = make_int2(base + st0, base + st0 + p0);   // padded range
      dinv[n0] = rsqrtf((float)(v0 + 1));
    }
    if (n1 < N) {
      rowse[n1] = make_int2(base + st1, base + st1 + p1);
      dinv[n1] = rsqrtf((float)(v1 + 1));
    }
  }
  __syncthreads();
  // sentinel-fill pad slots [start+v, start+p) — disjoint from scatter range
  if (tid < 128) {
    int v = hist[tid], st = starts[tid];
    int p = (v + 7) & ~7;
    for (int j = v; j < p; ++j) esort[base + st + j] = N;
  }
  for (int i = tid; i < cnt; i += 256) {
    int pk = eL[i];                       // LDS, not a global re-read
    int pos = atomicAdd(&curs[pk & 127], 1);
    esort[base + pos] = pk >> 7;
  }
}

// Pure GEMM: h1s = (x @ W1) * dinv. 256 thr = 4 waves x 16 rows = 64 rows per
// block. No LDS, no barriers; B-frags reloaded per kb from L2-hot W1t.
__global__ __launch_bounds__(256, 6) void kgemm1(
    const void* __restrict__ xraw, const u16* __restrict__ W1t,
    const int* __restrict__ mode, const float* __restrict__ dinv,
    u16* __restrict__ h1s, int N) {
  int tid = threadIdx.x;
  int mflag = mode[0];
  int lane = tid & 63, wv = tid >> 6;
  int m16 = lane & 15, q = lane >> 4;
  int row0 = blockIdx.x * 64 + wv * 16;

  f32x4 acc[4];
  #pragma unroll
  for (int jb = 0; jb < 4; ++jb) acc[jb] = (f32x4){0.f, 0.f, 0.f, 0.f};

  int rowm = row0 + m16;
  size_t rc = (size_t)((rowm < N) ? rowm : (N - 1));   // clamp loads only
  #pragma unroll
  for (int kb = 0; kb < 4; ++kb) {
    short8 a;
    if (mflag) {
      const float* xf = (const float*)xraw + rc * 128 + kb * 32 + q * 8;
      float4 u0 = ((const float4*)xf)[0];
      float4 u1 = ((const float4*)xf)[1];
      __hip_bfloat162 p0 = __float22bfloat162_rn(make_float2(u0.x, u0.y));
      __hip_bfloat162 p1 = __float22bfloat162_rn(make_float2(u0.z, u0.w));
      __hip_bfloat162 p2 = __float22bfloat162_rn(make_float2(u1.x, u1.y));
      __hip_bfloat162 p3 = __float22bfloat162_rn(make_float2(u1.z, u1.w));
      unsigned int w0 = *(const unsigned int*)&p0;
      unsigned int w1 = *(const unsigned int*)&p1;
      unsigned int w2 = *(const unsigned int*)&p2;
      unsigned int w3 = *(const unsigned int*)&p3;
      a[0] = (short)(w0 & 0xffff); a[1] = (short)(w0 >> 16);
      a[2] = (short)(w1 & 0xffff); a[3] = (short)(w1 >> 16);
      a[4] = (short)(w2 & 0xffff); a[5] = (short)(w2 >> 16);
      a[6] = (short)(w3 & 0xffff); a[7] = (short)(w3 >> 16);
    } else {
      a = *(const short8*)((const u16*)xraw + rc * 128 + kb * 32 + q * 8);
    }
    #pragma unroll
    for (int jb = 0; jb < 4; ++jb) {
      short8 bwf = *(const short8*)(W1t + (size_t)((kb * 4 + jb) * 64 + lane) * 8);
      acc[jb] = __builtin_amdgcn_mfma_f32_16x16x32_bf16(a, bwf, acc[jb], 0, 0, 0);
    }
  }

  // epilogue: dinv (one float4 per 4 rows; clamped), scale + store
  int r4 = row0 + q * 4;
  float4 dvv = (r4 + 3 < N) ? *(const float4*)(dinv + r4)
                            : make_float4(0.f, 0.f, 0.f, 0.f);
  float dv[4] = {dvv.x, dvv.y, dvv.z, dvv.w};
  if (r4 + 3 >= N) {
    #pragma unroll
    for (int r = 0; r < 4; ++r) dv[r] = (r4 + r < N) ? dinv[r4 + r] : 0.f;
  }
  #pragma unroll
  for (int r = 0; r < 4; ++r) {
    int rr = r4 + r;
    if (rr < N) {
      #pragma unroll
      for (int jb = 0; jb < 4; ++jb)
        h1s[(size_t)rr * 64 + jb * 16 + m16] = f2bf(acc[jb][r] * dv[r]);
    }
  }
}

// Pure layer-1 aggregate + relu + MFMA GEMM2. 256 thr = 4 waves, 64 nodes per
// block, NO __syncthreads (wave-local LDS only). Oct per node: lane fl owns
// features 8fl..8fl+7 (uint4 16B slice). Edge lists are 8-padded: pure chunk
// loop, 8 gathers in flight, no tail. Indices via coalesced load + shfl.
__global__ __launch_bounds__(256) void kagg1f(
    const u16* __restrict__ h1s, const int* __restrict__ esort,
    const int2* __restrict__ rowse, const float* __restrict__ dinv,
    const float* __restrict__ b1f, const u16* __restrict__ W2b,
    u16* __restrict__ h2sb, int N) {
  __shared__ __align__(16) u16 sA[4][16 * 72];  // wave-private bf16 tiles (9.2 KB)
  __shared__ float sdv[4][16];
  int tid = threadIdx.x;
  int lane = tid & 63, wv = tid >> 6;
  int o = lane >> 3, fl = lane & 7;             // oct index, feature-slice lane
  int wbase = blockIdx.x * 64 + wv * 16;        // this wave's 16 nodes

  const uint4* __restrict__ h1v4 = (const uint4*)h1s;

  #pragma unroll
  for (int sub = 0; sub < 2; ++sub) {
    int nloc = sub * 8 + o;
    int node = wbase + nloc;
    int cn = (node < N) ? node : (N - 1);       // clamp loads only
    int2 se = (node < N) ? rowse[node] : make_int2(0, 0);
    int beg = se.x, end = se.y;                 // padded range, multiple of 8
    float a0 = 0.f, a1 = 0.f, a2 = 0.f, a3 = 0.f;
    float a4 = 0.f, a5 = 0.f, a6 = 0.f, a7 = 0.f;

    int k = beg;
    int myi = (k < end) ? esort[k + fl] : 0;    // coalesced: 8 lanes, 8 ints
    while (k < end) {
      int cur = myi;
      int kn = k + 8;
      if (kn < end) myi = esort[kn + fl];       // prefetch next chunk's idx
      uint4 g[8];
      #pragma unroll
      for (int p = 0; p < 8; ++p) {
        int s = __shfl(cur, (o << 3) + p, 64);  // broadcast within oct
        g[p] = h1v4[s * 8 + fl];                // s==N -> zero sentinel row
      }
      #pragma unroll
      for (int p = 0; p < 8; ++p) {
        a0 += blo(g[p].x); a1 += bhi(g[p].x);
        a2 += blo(g[p].y); a3 += bhi(g[p].y);
        a4 += blo(g[p].z); a5 += bhi(g[p].z);
        a6 += blo(g[p].w); a7 += bhi(g[p].w);
      }
      k = kn;
    }

    uint4 sg = h1v4[cn * 8 + fl];                  // self row (pre-scaled)
    float dv = dinv[cn];
    float4 bva = ((const float4*)b1f)[fl * 2];
    float4 bvb = ((const float4*)b1f)[fl * 2 + 1];
    float v0 = fmaxf(dv * (a0 + blo(sg.x)) + bva.x, 0.f);
    float v1 = fmaxf(dv * (a1 + bhi(sg.x)) + bva.y, 0.f);
    float v2 = fmaxf(dv * (a2 + blo(sg.y)) + bva.z, 0.f);
    float v3 = fmaxf(dv * (a3 + bhi(sg.y)) + bva.w, 0.f);
    float v4 = fmaxf(dv * (a4 + blo(sg.z)) + bvb.x, 0.f);
    float v5 = fmaxf(dv * (a5 + bhi(sg.z)) + bvb.y, 0.f);
    float v6 = fmaxf(dv * (a6 + blo(sg.w)) + bvb.z, 0.f);
    float v7 = fmaxf(dv * (a7 + bhi(sg.w)) + bvb.w, 0.f);
    uint4 st;
    st.x = (unsigned int)f2bf(v0) | ((unsigned int)f2bf(v1) << 16);
    st.y = (unsigned int)f2bf(v2) | ((unsigned int)f2bf(v3) << 16);
    st.z = (unsigned int)f2bf(v4) | ((unsigned int)f2bf(v5) << 16);
    st.w = (unsigned int)f2bf(v6) | ((unsigned int)f2bf(v7) << 16);
    *(uint4*)&sA[wv][nloc * 72 + fl * 8] = st;     // 144B row stride, 16B aligned
    if (fl == 0) sdv[wv][nloc] = dv;
  }

  // GEMM2 B-frags built late to shrink live range (W2b is L2-hot).
  int m16 = lane & 15, q = lane >> 4;
  short8 bw0, bw1;
  #pragma unroll
  for (int j = 0; j < 8; ++j) {
    bw0[j] = (short)W2b[(q * 8 + j) * 16 + m16];
    bw1[j] = (short)W2b[(32 + q * 8 + j) * 16 + m16];
  }
  __builtin_amdgcn_wave_barrier();                 // order LDS write->read in-wave

  // MFMA: A[m=node 0..15][k=feature], one 16-node tile per wave.
  const u16* ar = &sA[wv][m16 * 72];
  short8 af0 = *(const short8*)(ar + q * 8);       // k = q*8+j
  short8 af1 = *(const short8*)(ar + 32 + q * 8);  // k = 32+q*8+j
  f32x4 c = (f32x4){0.f, 0.f, 0.f, 0.f};
  c = __builtin_amdgcn_mfma_f32_16x16x32_bf16(af0, bw0, c, 0, 0, 0);
  c = __builtin_amdgcn_mfma_f32_16x16x32_bf16(af1, bw1, c, 0, 0, 0);
  #pragma unroll
  for (int r = 0; r < 4; ++r) {
    int nloc2 = q * 4 + r;                         // D row = q*4+r, col = m16
    int nd2 = wbase + nloc2;
    if (nd2 < N) h2sb[(size_t)nd2 * 16 + m16] = f2bf(c[r] * sdv[wv][nloc2]);
  }
}

// Layer-2 aggregate + bias + relu + log_softmax.
// OCT per node; hl=(lane>>2)&1 = edge parity, fl=lane&3 = uint2 slice of the
// 32B row -> one load instr = 2 edges. Edge lists 8-padded: no tail.
// Width-4 softmax over 16 classes.
__global__ __launch_bounds__(256) void kagg2(
    const u16* __restrict__ h2sb, const int* __restrict__ esort,
    const int2* __restrict__ rowse, const float* __restrict__ dinv,
    const float* __restrict__ b2f, const int* __restrict__ mode,
    void* __restrict__ out, int n) {
  int mflag = mode[0];
  int tid = threadIdx.x;
  int lane = tid & 63, wv = tid >> 6;
  int oc = lane >> 3, ol = lane & 7;
  int hl = ol >> 2, fl = ol & 3;
  int node = blockIdx.x * 32 + wv * 8 + oc;
  if (node >= n) node = n - 1;
  int2 se = rowse[node];
  int beg = se.x, end = se.y;              // padded range, multiple of 8
  const uint2* h2v = (const uint2*)h2sb;   // 4 uint2 per 16-class row
  uint2 sg = h2v[node * 4 + fl];
  float a0 = 0.f, a1 = 0.f, a2 = 0.f, a3 = 0.f;

  for (int k = beg; k < end; k += 8) {     // 4 loads (8 edges) in flight
    int i0 = esort[k + hl], i1 = esort[k + 2 + hl];
    int i2 = esort[k + 4 + hl], i3 = esort[k + 6 + hl];
    uint2 g0 = h2v[i0 * 4 + fl];
    uint2 g1 = h2v[i1 * 4 + fl];
    uint2 g2 = h2v[i2 * 4 + fl];
    uint2 g3 = h2v[i3 * 4 + fl];
    a0 += bf2f((u16)(g0.x & 0xffff)) + bf2f((u16)(g1.x & 0xffff))
        + bf2f((u16)(g2.x & 0xffff)) + bf2f((u16)(g3.x & 0xffff));
    a1 += bf2f((u16)(g0.x >> 16)) + bf2f((u16)(g1.x >> 16))
        + bf2f((u16)(g2.x >> 16)) + bf2f((u16)(g3.x >> 16));
    a2 += bf2f((u16)(g0.y & 0xffff)) + bf2f((u16)(g1.y & 0xffff))
        + bf2f((u16)(g2.y & 0xffff)) + bf2f((u16)(g3.y & 0xffff));
    a3 += bf2f((u16)(g0.y >> 16)) + bf2f((u16)(g1.y >> 16))
        + bf2f((u16)(g2.y >> 16)) + bf2f((u16)(g3.y >> 16));
  }
  // combine edge-parity halves (lanes +-4 within the oct)
  a0 += __shfl_xor(a0, 4, 8);  a1 += __shfl_xor(a1, 4, 8);
  a2 += __shfl_xor(a2, 4, 8);  a3 += __shfl_xor(a3, 4, 8);

  float dv = dinv[node];
  float4 bv = ((const float4*)b2f)[fl];
  float v0 = fmaxf(dv * (a0 + bf2f((u16)(sg.x & 0xffff))) + bv.x, 0.f);
  float v1 = fmaxf(dv * (a1 + bf2f((u16)(sg.x >> 16))) + bv.y, 0.f);
  float v2 = fmaxf(dv * (a2 + bf2f((u16)(sg.y & 0xffff))) + bv.z, 0.f);
  float v3 = fmaxf(dv * (a3 + bf2f((u16)(sg.y >> 16))) + bv.w, 0.f);

  float m = fmaxf(fmaxf(v0, v1), fmaxf(v2, v3));
  m = fmaxf(m, __shfl_xor(m, 1, 4));
  m = fmaxf(m, __shfl_xor(m, 2, 4));
  float ex = __expf(v0 - m) + __expf(v1 - m) + __expf(v2 - m) + __expf(v3 - m);
  ex += __shfl_xor(ex, 1, 4);
  ex += __shfl_xor(ex, 2, 4);
  float lg = __logf(ex);
  float r0 = v0 - m - lg, r1 = v1 - m - lg;
  float r2 = v2 - m - lg, r3 = v3 - m - lg;
  if (hl == 0) {
    if (mflag) {
      ((float4*)out)[(size_t)node * 4 + fl] = make_float4(r0, r1, r2, r3);
    } else {
      uint2 o;
      o.x = (unsigned int)f2bf(r0) | ((unsigned int)f2bf(r1) << 16);
      o.y = (unsigned int)f2bf(r2) | ((unsigned int)f2bf(r3) << 16);
      ((uint2*)out)[(size_t)node * 4 + fl] = o;
    }
  }
}

extern "C" void kernel_launch(void* const* d_in, const int* in_sizes, int n_in,
                              void* d_out, int out_size, void* d_ws, size_t ws_size,
                              hipStream_t stream) {
  const void* x  = d_in[0];
  const int* ei  = (const int*)d_in[1];
  const void* W1 = d_in[2];
  const void* b1 = d_in[3];
  const void* W2 = d_in[4];
  const void* b2 = d_in[5];

  const int N = in_sizes[0] / 128;
  const int E = in_sizes[1] / 2;
  const int* src = ei;
  const int* dst = ei + E;
  const int NB = (N + 127) >> 7;          // 128-node buckets

  char* ws = (char*)d_ws;
  size_t off = 0;
  auto alloc = [&](size_t bytes) -> char* {
    char* p = ws + off;
    off = (off + bytes + 255) & ~(size_t)255;
    return p;
  };
  u16*   h1s    = (u16*)  alloc((size_t)(N + 1) * 64 * 2);  // +1 sentinel row
  u16*   h2sb   = (u16*)  alloc((size_t)(N + 1) * 16 * 2);  // +1 sentinel row
  int*   etmp   = (int*)  alloc((size_t)NB * CAP * 4);
  int*   esort  = (int*)  alloc((size_t)NB * CAP * 4);
  int2*  rowse  = (int2*) alloc((size_t)N * 8);
  float* dinv   = (float*)alloc((size_t)N * 4);
  int*   cursor = (int*)  alloc((size_t)NB * 4);
  u16*   W1t    = (u16*)  alloc(8192 * 2);
  u16*   W2b    = (u16*)  alloc(1024 * 2);
  float* b1f    = (float*)alloc(64 * 4);
  float* b2f    = (float*)alloc(16 * 4);
  int*   mode   = (int*)  alloc(4);

  hipMemsetAsync(cursor, 0, (size_t)NB * 4, stream);

  int pblocks = (E + 4095) / 4096;
  kpartc<<<pblocks + 1, 512, 0, stream>>>(src, dst, cursor, etmp,
                                          W1, b1, W2, b2,
                                          W1t, b1f, W2b, b2f, mode, E, NB);
  ksort<<<NB, 256, 0, stream>>>(etmp, cursor, dinv, esort, rowse,
                                h1s, h2sb, N);
  kgemm1<<<(N + 63) / 64, 256, 0, stream>>>(x, W1t, mode, dinv, h1s, N);
  kagg1f<<<(N + 63) / 64, 256, 0, stream>>>(h1s, esort, rowse, dinv, b1f, W2b,
                                            h2sb, N);
  kagg2<<<(N + 31) / 32, 256, 0, stream>>>(h2sb, esort, rowse, dinv, b2f, mode,
                                           d_out, N);
}